// Round 6
// baseline (661.392 us; speedup 1.0000x reference)
//
#include <hip/hip_runtime.h>
#include <math.h>

#define NE 8
#define HD 1024
#define FD 2048
#define NT 4096
#define NSLOT (NT * 2)

typedef __attribute__((ext_vector_type(8))) _Float16 half8;
typedef __attribute__((ext_vector_type(4))) float floatx4;

// in: [E][R][C] fp32 -> out: [E][C][R] fp16. 32r x 128c tile.
// Loads: float4 (16B/lane, coalesced). Stores: uint4 (16B/lane).
__global__ __launch_bounds__(256) void transpose_cvt(const float* __restrict__ in,
                                                     _Float16* __restrict__ outp,
                                                     int R, int C) {
  __shared__ float t[32][132];
  int e = blockIdx.z;
  int r0 = blockIdx.x * 32, c0 = blockIdx.y * 128;
  int tid = threadIdx.x;
  int f4c = tid & 31, rr = tid >> 5;  // col-quad 0..31, row 0..7
  const float* src = in + (size_t)e * R * C;
#pragma unroll
  for (int i = 0; i < 4; i++) {
    float4 v = *(const float4*)(src + (size_t)(r0 + rr + 8 * i) * C + c0 + f4c * 4);
    *(float4*)&t[rr + 8 * i][f4c * 4] = v;
  }
  __syncthreads();
  _Float16* dst = outp + (size_t)e * R * C;
  int oc = tid >> 1, rh = (tid & 1) * 16;  // out-col 0..127, row-half 0/16
  union { _Float16 h[8]; uint4 v; } o;
#pragma unroll
  for (int k2 = 0; k2 < 2; k2++) {
#pragma unroll
    for (int k = 0; k < 8; k++) o.h[k] = (_Float16)t[rh + k2 * 8 + k][oc];
    *(uint4*)(dst + (size_t)(c0 + oc) * R + r0 + rh + k2 * 8) = o.v;
  }
}

// ---------------- router (also emits fp16 copy of x) ----------------
__global__ __launch_bounds__(256) void router_probs_kernel(
    const float* __restrict__ x, const float* __restrict__ rw, _Float16* __restrict__ xh,
    float* __restrict__ probs, int* __restrict__ sel_e, float* __restrict__ sel_w) {
  int n = blockIdx.x * 4 + (threadIdx.x >> 6);
  int lane = threadIdx.x & 63;
  const float* xr = x + (size_t)n * HD;
  float xv[16];
#pragma unroll
  for (int t = 0; t < 16; t++) xv[t] = xr[lane + 64 * t];
  _Float16* xhr = xh + (size_t)n * HD;
#pragma unroll
  for (int t = 0; t < 16; t++) xhr[lane + 64 * t] = (_Float16)xv[t];
  float logits[NE];
#pragma unroll
  for (int e = 0; e < NE; e++) {
    const float* w = rw + (size_t)e * HD;
    float acc = 0.f;
#pragma unroll
    for (int t = 0; t < 16; t++) acc += xv[t] * w[lane + 64 * t];
    for (int off = 32; off > 0; off >>= 1) acc += __shfl_down(acc, off);
    logits[e] = acc;
  }
  if (lane == 0) {
    float mx = logits[0];
#pragma unroll
    for (int e = 1; e < NE; e++) mx = fmaxf(mx, logits[e]);
    float p[NE]; float s = 0.f;
#pragma unroll
    for (int e = 0; e < NE; e++) { p[e] = expf(logits[e] - mx); s += p[e]; }
    float inv = 1.f / s;
#pragma unroll
    for (int e = 0; e < NE; e++) { p[e] *= inv; probs[n * NE + e] = p[e]; }
    int i1 = 0;
#pragma unroll
    for (int e = 1; e < NE; e++) if (p[e] > p[i1]) i1 = e;
    int i2 = -1; float p2 = -1.f;
#pragma unroll
    for (int e = 0; e < NE; e++) {
      if (e == i1) continue;
      if (p[e] > p2) { p2 = p[e]; i2 = e; }
    }
    float wn = 1.f / (p[i1] + p[i2]);
    sel_e[n * 2 + 0] = i1; sel_w[n * 2 + 0] = p[i1] * wn;
    sel_e[n * 2 + 1] = i2; sel_w[n * 2 + 1] = p[i2] * wn;
  }
}

__global__ __launch_bounds__(1024) void router_reduce_kernel(
    const float* __restrict__ probs, const int* __restrict__ sel_e,
    int* __restrict__ counts, int* __restrict__ offs, int* __restrict__ cursor,
    float* __restrict__ aux_out) {
  int t = threadIdx.x;
  int lane = t & 63, wave = t >> 6;
  float ps[NE];
  int cn[NE];
#pragma unroll
  for (int e = 0; e < NE; e++) { ps[e] = 0.f; cn[e] = 0; }
  for (int r = t; r < NT; r += 1024) {
    const float* pr = probs + (size_t)r * NE;
#pragma unroll
    for (int e = 0; e < NE; e++) ps[e] += pr[e];
  }
  for (int i = t; i < NSLOT; i += 1024) {
    int e = sel_e[i];
#pragma unroll
    for (int j = 0; j < NE; j++) cn[j] += (e == j) ? 1 : 0;
  }
  for (int off = 32; off > 0; off >>= 1) {
#pragma unroll
    for (int e = 0; e < NE; e++) {
      ps[e] += __shfl_down(ps[e], off);
      cn[e] += __shfl_down(cn[e], off);
    }
  }
  __shared__ float sps[16][NE];
  __shared__ int scn[16][NE];
  if (lane == 0) {
#pragma unroll
    for (int e = 0; e < NE; e++) { sps[wave][e] = ps[e]; scn[wave][e] = cn[e]; }
  }
  __syncthreads();
  if (t == 0) {
    float tot_p[NE]; int tot_c[NE];
#pragma unroll
    for (int e = 0; e < NE; e++) { tot_p[e] = 0.f; tot_c[e] = 0; }
    for (int w = 0; w < 16; w++)
#pragma unroll
      for (int e = 0; e < NE; e++) { tot_p[e] += sps[w][e]; tot_c[e] += scn[w][e]; }
    int o = 0;
    float aux = 0.f;
    for (int e = 0; e < NE; e++) {
      counts[e] = tot_c[e];
      offs[e] = o; o += tot_c[e];
      cursor[e] = 0;
      aux += ((float)tot_c[e] / (float)NSLOT) * (tot_p[e] / (float)NT);
    }
    aux_out[0] = (float)NE * aux;
  }
}

__global__ __launch_bounds__(256) void build_gather(
    const int* __restrict__ sel_e, const float* __restrict__ sel_w,
    const int* __restrict__ offs, int* __restrict__ cursor,
    int* __restrict__ gtok, float* __restrict__ gw, int* __restrict__ srow) {
  __shared__ int lh[NE], lbase[NE];
  int t = threadIdx.x;
  int i = blockIdx.x * 256 + t;
  if (t < NE) lh[t] = 0;
  __syncthreads();
  int e = sel_e[i];
  int lrank = atomicAdd(&lh[e], 1);
  __syncthreads();
  if (t < NE) lbase[t] = atomicAdd(&cursor[t], lh[t]);
  __syncthreads();
  int row = offs[e] + lbase[e] + lrank;
  gtok[row] = i >> 1;
  gw[row] = sel_w[i];
  srow[i] = row;
}

// ---------------- grouped GEMM: LDS-free, direct L2->VGPR fragments ----------------
// BM=BN=128, BK=64, 256 thr = 4 waves (2x2). NO LDS, NO barriers: per-XCD working
// set (A panel ~2-4MB + hot B panels) is L2-resident, so staging through LDS was
// pure serialization (R0-R4: 65% of cycles stalled at barrier/vmcnt drains; per-wave
// throughput invariant to pipelining). Each wave loads its MFMA fragments directly:
// per load inst, lanes fr=0..15 x g=0..3 touch 16 rows x 64B contiguous; waves
// sharing rows (2-way for A and B) hit L1/L2. Compiler pipelines freely (no fences).
// Cost: 2x L2 read amplification vs LDS - cheap vs the removed stalls.
template <int KDIM, int NDIM, bool IS_UP>
__global__ __launch_bounds__(256, 4) void moe_gemm_d(
    const _Float16* __restrict__ Abase, const _Float16* __restrict__ Bt,
    const int* __restrict__ counts, const int* __restrict__ offs,
    const int* __restrict__ gtok, const float* __restrict__ gw,
    _Float16* __restrict__ Hout, float* __restrict__ Dout) {
  int e = blockIdx.x;
  int cnt = counts[e];
  int m0 = blockIdx.y * 128;
  if (m0 >= cnt) return;
  int n0 = blockIdx.z * 128;
  int off = offs[e];

  int lane = threadIdx.x & 63, wave = threadIdx.x >> 6;
  int wm = (wave >> 1) * 64, wn = (wave & 1) * 64;
  int fr = lane & 15, g = lane >> 4;

  // per-lane global fragment pointers (4 A rows, 4 B rows; k-chunk g)
  const _Float16* ap[4];
  const _Float16* bp[4];
#pragma unroll
  for (int t = 0; t < 4; t++) {
    int am = m0 + wm + t * 16 + fr;
    if (am > cnt - 1) am = cnt - 1;  // clamp tail (masked at epilogue)
    if (IS_UP) {
      ap[t] = Abase + (size_t)gtok[off + am] * KDIM + g * 8;
    } else {
      ap[t] = Abase + (size_t)(off + am) * KDIM + g * 8;
    }
    bp[t] = Bt + ((size_t)e * NDIM + n0 + wn + t * 16 + fr) * KDIM + g * 8;
  }

  floatx4 acc[4][4];
#pragma unroll
  for (int i = 0; i < 4; i++)
#pragma unroll
    for (int j = 0; j < 4; j++) acc[i][j] = (floatx4){0.f, 0.f, 0.f, 0.f};

  for (int kt = 0; kt < KDIM / 64; kt++) {
    half8 af[4], bfv[4];
    // sub-step 0: k in [kt*64, kt*64+32)
#pragma unroll
    for (int t = 0; t < 4; t++) {
      af[t] = *(const half8*)(ap[t]);
      bfv[t] = *(const half8*)(bp[t]);
    }
#pragma unroll
    for (int i = 0; i < 4; i++)
#pragma unroll
      for (int j = 0; j < 4; j++)
        acc[i][j] = __builtin_amdgcn_mfma_f32_16x16x32_f16(af[i], bfv[j], acc[i][j], 0, 0, 0);
    // sub-step 1: k in [kt*64+32, kt*64+64)
#pragma unroll
    for (int t = 0; t < 4; t++) {
      af[t] = *(const half8*)(ap[t] + 32);
      bfv[t] = *(const half8*)(bp[t] + 32);
    }
#pragma unroll
    for (int i = 0; i < 4; i++)
#pragma unroll
      for (int j = 0; j < 4; j++)
        acc[i][j] = __builtin_amdgcn_mfma_f32_16x16x32_f16(af[i], bfv[j], acc[i][j], 0, 0, 0);
#pragma unroll
    for (int t = 0; t < 4; t++) { ap[t] += 64; bp[t] += 64; }
  }

  // epilogue: D layout col=lane&15, row=(lane>>4)*4+r
  int cq = (lane >> 4) * 4, cc = lane & 15;
#pragma unroll
  for (int i = 0; i < 4; i++) {
#pragma unroll
    for (int r = 0; r < 4; r++) {
      int m = wm + i * 16 + cq + r;
      if (m0 + m < cnt) {
        if (IS_UP) {
          float w = gw[off + m0 + m];
          _Float16* hrow = Hout + (size_t)(off + m0 + m) * NDIM + n0;
#pragma unroll
          for (int j = 0; j < 4; j++) {
            float v = acc[i][j][r];
            float gl = 0.5f * v * (1.f + erff(v * 0.70710678118f));
            hrow[wn + j * 16 + cc] = (_Float16)(gl * w);
          }
        } else {
          float* orow = Dout + (size_t)(off + m0 + m) * NDIM + n0;
#pragma unroll
          for (int j = 0; j < 4; j++) orow[wn + j * 16 + cc] = acc[i][j][r];
        }
      }
    }
  }
}

__global__ __launch_bounds__(256) void combine_kernel(
    const float* __restrict__ Dout, const int* __restrict__ srow,
    float* __restrict__ out) {
  int n = blockIdx.x;
  int t = threadIdx.x;
  int r0 = srow[n * 2], r1 = srow[n * 2 + 1];
  float4 a = *(const float4*)(Dout + (size_t)r0 * HD + t * 4);
  float4 b = *(const float4*)(Dout + (size_t)r1 * HD + t * 4);
  float4 c; c.x = a.x + b.x; c.y = a.y + b.y; c.z = a.z + b.z; c.w = a.w + b.w;
  *(float4*)(out + (size_t)n * HD + t * 4) = c;
}

// ---------------- launch ----------------
extern "C" void kernel_launch(void* const* d_in, const int* in_sizes, int n_in,
                              void* d_out, int out_size, void* d_ws, size_t ws_size,
                              hipStream_t stream) {
  const float* x = (const float*)d_in[0];     // [4096,1024]
  const float* rw = (const float*)d_in[1];    // [8,1024]
  const float* up_w = (const float*)d_in[2];  // [8,1024,2048]
  const float* dn_w = (const float*)d_in[3];  // [8,2048,1024]
  float* out = (float*)d_out;                 // [4096*1024] ++ [1]

  char* ws = (char*)d_ws;
  _Float16* Xh   = (_Float16*)(ws + 0);          // 8 MB  (dead after up-GEMM)
  _Float16* Wut  = (_Float16*)(ws + 8388608);    // 32 MB (dead after up-GEMM)
  float*    Dout = (float*)(ws + 0);             // 32 MB ALIAS over Xh+Wut
  _Float16* Wdt  = (_Float16*)(ws + 41943040);   // 32 MB [8][1024][2048]
  _Float16* Hbuf = (_Float16*)(ws + 75497472);   // 32 MB [8192][2048]
  char* tail = ws + 109051904;
  int*   gtok   = (int*)(tail + 0);        // 32 KB
  float* gw     = (float*)(tail + 32768);  // 32 KB
  int*   sel_e  = (int*)(tail + 65536);    // 32 KB
  float* sel_w  = (float*)(tail + 98304);  // 32 KB
  int*   srow   = (int*)(tail + 131072);   // 32 KB
  float* probs  = (float*)(tail + 163840); // 128 KB
  int*   counts = (int*)(tail + 294912);
  int*   offs   = (int*)(tail + 294944);
  int*   cursor = (int*)(tail + 294976);

  transpose_cvt<<<dim3(HD / 32, FD / 128, NE), 256, 0, stream>>>(up_w, Wut, HD, FD);
  transpose_cvt<<<dim3(FD / 32, HD / 128, NE), 256, 0, stream>>>(dn_w, Wdt, FD, HD);
  router_probs_kernel<<<NT / 4, 256, 0, stream>>>(x, rw, Xh, probs, sel_e, sel_w);
  router_reduce_kernel<<<1, 1024, 0, stream>>>(probs, sel_e, counts, offs, cursor,
                                               out + (size_t)NT * HD);
  build_gather<<<NSLOT / 256, 256, 0, stream>>>(sel_e, sel_w, offs, cursor, gtok, gw, srow);

  // up: A=[gathered Xh] (K=1024), B=Wut (N=2048) -> Hbuf. Grid (e, m, n): XCD-pinned.
  moe_gemm_d<HD, FD, true><<<dim3(NE, 32, FD / 128), 256, 0, stream>>>(
      Xh, Wut, counts, offs, gtok, gw, Hbuf, nullptr);
  // down: A=Hbuf (K=2048), B=Wdt (N=1024) -> Dout fp32 per slot. XCD-pinned.
  moe_gemm_d<FD, HD, false><<<dim3(NE, 32, HD / 128), 256, 0, stream>>>(
      Hbuf, Wdt, counts, offs, gtok, gw, nullptr, Dout);
  combine_kernel<<<NT, 256, 0, stream>>>(Dout, srow, out);
}

// Round 7
// 319.694 us; speedup vs baseline: 2.0688x; 2.0688x over previous
//
#include <hip/hip_runtime.h>
#include <math.h>

#define NE 8
#define HD 1024
#define FD 2048
#define NT 4096
#define NSLOT (NT * 2)

typedef __attribute__((ext_vector_type(8))) _Float16 half8;
typedef __attribute__((ext_vector_type(4))) float floatx4;

// async global->LDS, 16B per lane. LDS dest is wave-uniform base + lane*16.
__device__ __forceinline__ void gload_lds(const _Float16* g, _Float16* l) {
  __builtin_amdgcn_global_load_lds(
      (const __attribute__((address_space(1))) unsigned int*)g,
      (__attribute__((address_space(3))) unsigned int*)l, 16, 0, 0);
}

// Both weight transposes in ONE launch. [E][R][C] fp32 -> [E][C][R] fp16.
// blocks 0..4095: up_w (R=HD,C=FD); 4096..8191: dn_w (R=FD,C=HD).
// 32r x 128c tile; float4 loads (16B/lane), uint4 stores (16B/lane).
__global__ __launch_bounds__(256) void transpose_cvt_all(
    const float* __restrict__ up_w, _Float16* __restrict__ wut,
    const float* __restrict__ dn_w, _Float16* __restrict__ wdt) {
  __shared__ float t[32][132];
  int b = blockIdx.x;
  const float* in;
  _Float16* outp;
  int R, C, rem;
  if (b < 4096) {
    R = HD; C = FD; in = up_w; outp = wut;
    int e = b >> 9; rem = b & 511;
    in += (size_t)e * R * C; outp += (size_t)e * R * C;
  } else {
    int b2 = b - 4096;
    R = FD; C = HD; in = dn_w; outp = wdt;
    int e = b2 >> 9; rem = b2 & 511;
    in += (size_t)e * R * C; outp += (size_t)e * R * C;
  }
  int nx = R / 32;                       // 32 (up) or 64 (down)
  int r0 = (rem % nx) * 32, c0 = (rem / nx) * 128;
  int tid = threadIdx.x;
  int f4c = tid & 31, rr = tid >> 5;  // col-quad 0..31, row 0..7
#pragma unroll
  for (int i = 0; i < 4; i++) {
    float4 v = *(const float4*)(in + (size_t)(r0 + rr + 8 * i) * C + c0 + f4c * 4);
    *(float4*)&t[rr + 8 * i][f4c * 4] = v;
  }
  __syncthreads();
  int oc = tid >> 1, rh = (tid & 1) * 16;  // out-col 0..127, row-half 0/16
  union { _Float16 h[8]; uint4 v; } o;
#pragma unroll
  for (int k2 = 0; k2 < 2; k2++) {
#pragma unroll
    for (int k = 0; k < 8; k++) o.h[k] = (_Float16)t[rh + k2 * 8 + k][oc];
    *(uint4*)(outp + (size_t)(c0 + oc) * R + r0 + rh + k2 * 8) = o.v;
  }
}

// ---------------- router (also emits fp16 copy of x) ----------------
__global__ __launch_bounds__(256) void router_probs_kernel(
    const float* __restrict__ x, const float* __restrict__ rw, _Float16* __restrict__ xh,
    float* __restrict__ probs, int* __restrict__ sel_e, float* __restrict__ sel_w) {
  int n = blockIdx.x * 4 + (threadIdx.x >> 6);
  int lane = threadIdx.x & 63;
  const float* xr = x + (size_t)n * HD;
  float xv[16];
#pragma unroll
  for (int t = 0; t < 16; t++) xv[t] = xr[lane + 64 * t];
  _Float16* xhr = xh + (size_t)n * HD;
#pragma unroll
  for (int t = 0; t < 16; t++) xhr[lane + 64 * t] = (_Float16)xv[t];
  float logits[NE];
#pragma unroll
  for (int e = 0; e < NE; e++) {
    const float* w = rw + (size_t)e * HD;
    float acc = 0.f;
#pragma unroll
    for (int t = 0; t < 16; t++) acc += xv[t] * w[lane + 64 * t];
    for (int off = 32; off > 0; off >>= 1) acc += __shfl_down(acc, off);
    logits[e] = acc;
  }
  if (lane == 0) {
    float mx = logits[0];
#pragma unroll
    for (int e = 1; e < NE; e++) mx = fmaxf(mx, logits[e]);
    float p[NE]; float s = 0.f;
#pragma unroll
    for (int e = 0; e < NE; e++) { p[e] = expf(logits[e] - mx); s += p[e]; }
    float inv = 1.f / s;
#pragma unroll
    for (int e = 0; e < NE; e++) { p[e] *= inv; probs[n * NE + e] = p[e]; }
    int i1 = 0;
#pragma unroll
    for (int e = 1; e < NE; e++) if (p[e] > p[i1]) i1 = e;
    int i2 = -1; float p2 = -1.f;
#pragma unroll
    for (int e = 0; e < NE; e++) {
      if (e == i1) continue;
      if (p[e] > p2) { p2 = p[e]; i2 = e; }
    }
    float wn = 1.f / (p[i1] + p[i2]);
    sel_e[n * 2 + 0] = i1; sel_w[n * 2 + 0] = p[i1] * wn;
    sel_e[n * 2 + 1] = i2; sel_w[n * 2 + 1] = p[i2] * wn;
  }
}

// ---------------- reduce + gather build (single block, fused) ----------------
__global__ __launch_bounds__(1024) void router_reduce_gather(
    const float* __restrict__ probs, const int* __restrict__ sel_e,
    const float* __restrict__ sel_w,
    int* __restrict__ counts, int* __restrict__ offs,
    int* __restrict__ gtok, float* __restrict__ gw, int* __restrict__ srow,
    float* __restrict__ aux_out) {
  int t = threadIdx.x;
  int lane = t & 63, wave = t >> 6;
  float ps[NE];
  int cn[NE];
#pragma unroll
  for (int e = 0; e < NE; e++) { ps[e] = 0.f; cn[e] = 0; }
  for (int r = t; r < NT; r += 1024) {
    const float* pr = probs + (size_t)r * NE;
#pragma unroll
    for (int e = 0; e < NE; e++) ps[e] += pr[e];
  }
  for (int i = t; i < NSLOT; i += 1024) {
    int e = sel_e[i];
#pragma unroll
    for (int j = 0; j < NE; j++) cn[j] += (e == j) ? 1 : 0;
  }
  for (int off = 32; off > 0; off >>= 1) {
#pragma unroll
    for (int e = 0; e < NE; e++) {
      ps[e] += __shfl_down(ps[e], off);
      cn[e] += __shfl_down(cn[e], off);
    }
  }
  __shared__ float sps[16][NE];
  __shared__ int scn[16][NE];
  __shared__ int s_offs[NE];
  __shared__ int s_cur[NE];
  if (lane == 0) {
#pragma unroll
    for (int e = 0; e < NE; e++) { sps[wave][e] = ps[e]; scn[wave][e] = cn[e]; }
  }
  __syncthreads();
  if (t == 0) {
    float tot_p[NE]; int tot_c[NE];
#pragma unroll
    for (int e = 0; e < NE; e++) { tot_p[e] = 0.f; tot_c[e] = 0; }
    for (int w = 0; w < 16; w++)
#pragma unroll
      for (int e = 0; e < NE; e++) { tot_p[e] += sps[w][e]; tot_c[e] += scn[w][e]; }
    int o = 0;
    float aux = 0.f;
    for (int e = 0; e < NE; e++) {
      counts[e] = tot_c[e];
      offs[e] = o; s_offs[e] = o; o += tot_c[e];
      s_cur[e] = 0;
      aux += ((float)tot_c[e] / (float)NSLOT) * (tot_p[e] / (float)NT);
    }
    aux_out[0] = (float)NE * aux;
  }
  __syncthreads();
  // slot assignment: any order within an expert region is valid
  for (int i = t; i < NSLOT; i += 1024) {
    int e = sel_e[i];
    int rank = atomicAdd(&s_cur[e], 1);
    int row = s_offs[e] + rank;
    gtok[row] = i >> 1;
    gw[row] = sel_w[i];
    srow[i] = row;
  }
}

// ---------------- grouped GEMM (R0 core, verified 3x) ----------------
// BM=BN=128, BK=64, 256 thr = 4 waves, 32 KB LDS, launch_bounds(256,3).
// R0-R6 established: the serial per-K-step DMA chain is hidden only by
// cross-block TLP; pipelining variants (R1 dbuf, R2 256^2) and LDS-free
// direct loads (R6: MfmaUtil 5.7%, VALUBusy 2%) all lose. Keep exact.
template <int KDIM, int NDIM, bool IS_UP>
__global__ __launch_bounds__(256, 3) void moe_gemm2(
    const _Float16* __restrict__ Abase, const _Float16* __restrict__ Bt,
    const int* __restrict__ counts, const int* __restrict__ offs,
    const int* __restrict__ gtok, const float* __restrict__ gw,
    _Float16* __restrict__ Hout, float* __restrict__ Dout) {
  int e = blockIdx.x;
  int cnt = counts[e];
  int m0 = blockIdx.y * 128;
  if (m0 >= cnt) return;
  int n0 = blockIdx.z * 128;
  int off = offs[e];

  __shared__ __align__(16) _Float16 As[128 * 64];  // 16 KB
  __shared__ __align__(16) _Float16 Bs[128 * 64];  // 16 KB

  int tid = threadIdx.x;
  int lane = tid & 63, wave = tid >> 6;
  int wm = (wave >> 1) * 64, wn = (wave & 1) * 64;

  // staging: wave stages rows [wave*32, wave*32+32), 8 rows per dma insn
  int srow8 = lane >> 3;            // row within 8-row group
  int chunk = (lane & 7) ^ srow8;   // logical 16B chunk this lane fetches
  const _Float16* ga[4];
  const _Float16* gb[4];
  _Float16* lA[4];
  _Float16* lB[4];
#pragma unroll
  for (int j = 0; j < 4; j++) {
    int r = wave * 32 + j * 8 + srow8;  // 0..127 tile row
    int am = m0 + r;
    if (am > cnt - 1) am = cnt - 1;  // clamp tail (masked at epilogue)
    if (IS_UP) {
      ga[j] = Abase + (size_t)gtok[off + am] * KDIM + chunk * 8;
    } else {
      ga[j] = Abase + (size_t)(off + am) * KDIM + chunk * 8;
    }
    gb[j] = Bt + ((size_t)e * NDIM + n0 + r) * KDIM + chunk * 8;
    lA[j] = As + (wave * 32 + j * 8) * 64;
    lB[j] = Bs + (wave * 32 + j * 8) * 64;
  }

  floatx4 acc[4][4];
#pragma unroll
  for (int i = 0; i < 4; i++)
#pragma unroll
    for (int j = 0; j < 4; j++) acc[i][j] = (floatx4){0.f, 0.f, 0.f, 0.f};

  int fr = lane & 15, g = lane >> 4;
  int sw0 = ((g) ^ (fr & 7)) * 8;      // substep 0: logical chunk g
  int sw1 = ((4 + g) ^ (fr & 7)) * 8;  // substep 1: logical chunk 4+g

  for (int kt = 0; kt < KDIM / 64; kt++) {
    __syncthreads();  // previous tile's reads done before overwrite
#pragma unroll
    for (int j = 0; j < 4; j++) gload_lds(ga[j], lA[j]);
#pragma unroll
    for (int j = 0; j < 4; j++) gload_lds(gb[j], lB[j]);
#pragma unroll
    for (int j = 0; j < 4; j++) { ga[j] += 64; gb[j] += 64; }
    __syncthreads();  // drains vmcnt -> tiles visible

    half8 af[4], bfv[4];
#pragma unroll
    for (int t = 0; t < 4; t++) {
      af[t] = *(const half8*)(As + (wm + t * 16 + fr) * 64 + sw0);
      bfv[t] = *(const half8*)(Bs + (wn + t * 16 + fr) * 64 + sw0);
    }
#pragma unroll
    for (int i = 0; i < 4; i++)
#pragma unroll
      for (int j = 0; j < 4; j++)
        acc[i][j] = __builtin_amdgcn_mfma_f32_16x16x32_f16(af[i], bfv[j], acc[i][j], 0, 0, 0);
#pragma unroll
    for (int t = 0; t < 4; t++) {
      af[t] = *(const half8*)(As + (wm + t * 16 + fr) * 64 + sw1);
      bfv[t] = *(const half8*)(Bs + (wn + t * 16 + fr) * 64 + sw1);
    }
#pragma unroll
    for (int i = 0; i < 4; i++)
#pragma unroll
      for (int j = 0; j < 4; j++)
        acc[i][j] = __builtin_amdgcn_mfma_f32_16x16x32_f16(af[i], bfv[j], acc[i][j], 0, 0, 0);
  }

  // epilogue: D layout col=lane&15, row=(lane>>4)*4+r
  int cq = (lane >> 4) * 4, cc = lane & 15;
#pragma unroll
  for (int i = 0; i < 4; i++) {
#pragma unroll
    for (int r = 0; r < 4; r++) {
      int m = wm + i * 16 + cq + r;
      if (m0 + m < cnt) {
        if (IS_UP) {
          float w = gw[off + m0 + m];
          _Float16* hrow = Hout + (size_t)(off + m0 + m) * NDIM + n0;
#pragma unroll
          for (int j = 0; j < 4; j++) {
            float v = acc[i][j][r];
            float gl = 0.5f * v * (1.f + erff(v * 0.70710678118f));
            hrow[wn + j * 16 + cc] = (_Float16)(gl * w);
          }
        } else {
          float* orow = Dout + (size_t)(off + m0 + m) * NDIM + n0;
#pragma unroll
          for (int j = 0; j < 4; j++) orow[wn + j * 16 + cc] = acc[i][j][r];
        }
      }
    }
  }
}

__global__ __launch_bounds__(256) void combine_kernel(
    const float* __restrict__ Dout, const int* __restrict__ srow,
    float* __restrict__ out) {
  int n = blockIdx.x;
  int t = threadIdx.x;
  int r0 = srow[n * 2], r1 = srow[n * 2 + 1];
  float4 a = *(const float4*)(Dout + (size_t)r0 * HD + t * 4);
  float4 b = *(const float4*)(Dout + (size_t)r1 * HD + t * 4);
  float4 c; c.x = a.x + b.x; c.y = a.y + b.y; c.z = a.z + b.z; c.w = a.w + b.w;
  *(float4*)(out + (size_t)n * HD + t * 4) = c;
}

// ---------------- launch ----------------
extern "C" void kernel_launch(void* const* d_in, const int* in_sizes, int n_in,
                              void* d_out, int out_size, void* d_ws, size_t ws_size,
                              hipStream_t stream) {
  const float* x = (const float*)d_in[0];     // [4096,1024]
  const float* rw = (const float*)d_in[1];    // [8,1024]
  const float* up_w = (const float*)d_in[2];  // [8,1024,2048]
  const float* dn_w = (const float*)d_in[3];  // [8,2048,1024]
  float* out = (float*)d_out;                 // [4096*1024] ++ [1]

  char* ws = (char*)d_ws;
  _Float16* Xh   = (_Float16*)(ws + 0);          // 8 MB  (dead after up-GEMM)
  _Float16* Wut  = (_Float16*)(ws + 8388608);    // 32 MB (dead after up-GEMM)
  float*    Dout = (float*)(ws + 0);             // 32 MB ALIAS over Xh+Wut
  _Float16* Wdt  = (_Float16*)(ws + 41943040);   // 32 MB [8][1024][2048]
  _Float16* Hbuf = (_Float16*)(ws + 75497472);   // 32 MB [8192][2048]
  char* tail = ws + 109051904;
  int*   gtok   = (int*)(tail + 0);        // 32 KB
  float* gw     = (float*)(tail + 32768);  // 32 KB
  int*   sel_e  = (int*)(tail + 65536);    // 32 KB
  float* sel_w  = (float*)(tail + 98304);  // 32 KB
  int*   srow   = (int*)(tail + 131072);   // 32 KB
  float* probs  = (float*)(tail + 163840); // 128 KB
  int*   counts = (int*)(tail + 294912);
  int*   offs   = (int*)(tail + 294944);

  // 1: both weight transposes, one launch
  transpose_cvt_all<<<8192, 256, 0, stream>>>(up_w, Wut, dn_w, Wdt);
  // 2: router probs + top-2 + fp16 x copy
  router_probs_kernel<<<NT / 4, 256, 0, stream>>>(x, rw, Xh, probs, sel_e, sel_w);
  // 3: aux loss + counts/offs + gather lists (fused, one block)
  router_reduce_gather<<<1, 1024, 0, stream>>>(probs, sel_e, sel_w, counts, offs,
                                               gtok, gw, srow, out + (size_t)NT * HD);
  // 4: up-GEMM. A=[gathered Xh] (K=1024), B=Wut (N=2048) -> Hbuf. XCD-pinned grid.
  moe_gemm2<HD, FD, true><<<dim3(NE, 32, FD / 128), 256, 0, stream>>>(
      Xh, Wut, counts, offs, gtok, gw, Hbuf, nullptr);
  // 5: down-GEMM. A=Hbuf (K=2048), B=Wdt (N=1024) -> Dout fp32 per slot.
  moe_gemm2<FD, HD, false><<<dim3(NE, 32, HD / 128), 256, 0, stream>>>(
      Hbuf, Wdt, counts, offs, gtok, gw, nullptr, Dout);
  // 6: per-token top-2 sum
  combine_kernel<<<NT, 256, 0, stream>>>(Dout, srow, out);
}